// Round 1
// baseline (1768.737 us; speedup 1.0000x reference)
//
#include <hip/hip_runtime.h>

// Problem: TreeLRU. B=16, N=4095 (heap), IN=OUT=512, S=256.
// Pipeline:
//   prep_M:   M[512][512] = [gamma*B_re@W_in ; gamma*B_im@W_in]   (K=512 over IN_F index i)
//   prep_bias:biasc[512]  = gamma * (b_in @ B^T)  (re|im stacked)
//   prep_C:   Cc[512][512]= [C_re | -C_im] per output row
//   gemm1:    hbuf[65520][512] = x @ M^T + biasc   (= gamma*in, which IS h at the leaves)
//   recur:    in-place bottom-up complex tree recurrence, levels 10..0
//   gemm2:    out = hbuf @ Cc^T
// All fp32 (baseline; MFMA conversion in later rounds).

#define ROWS 65520          // 16 * 4095
#define KDIM 512
#define NCOLS 512

// ---------------- precompute M ----------------
__global__ __launch_bounds__(256) void prep_M(const float* __restrict__ W,
                                              const float* __restrict__ Bre,
                                              const float* __restrict__ Bim,
                                              const float* __restrict__ gamma_log,
                                              float* __restrict__ M) {
    __shared__ float Bs[16][17];
    __shared__ float Ws[16][17];
    int tx = threadIdx.x, ty = threadIdx.y;
    int j  = blockIdx.x * 16 + tx;      // output inner-feature col
    int cc = blockIdx.y * 16 + ty;      // combined state row (0..255 re, 256..511 im)
    const float* Bsel = (cc < 256) ? (Bre + (size_t)cc * 512)
                                   : (Bim + (size_t)(cc - 256) * 512);
    float acc = 0.f;
    for (int kt = 0; kt < 512; kt += 16) {
        Bs[ty][tx] = Bsel[kt + tx];
        Ws[ty][tx] = W[(size_t)(kt + ty) * 512 + j];
        __syncthreads();
#pragma unroll
        for (int k = 0; k < 16; ++k) acc += Bs[ty][k] * Ws[k][tx];
        __syncthreads();
    }
    float g = __expf(0.f); // placeholder avoided; compute real gamma below
    g = expf(gamma_log[cc & 255]);
    M[(size_t)cc * 512 + j] = acc * g;
}

// ---------------- precompute bias ----------------
__global__ void prep_bias(const float* __restrict__ bin,
                          const float* __restrict__ Bre,
                          const float* __restrict__ Bim,
                          const float* __restrict__ gamma_log,
                          float* __restrict__ biasc) {
    int c = threadIdx.x;  // 0..511
    const float* Bsel = (c < 256) ? (Bre + (size_t)c * 512)
                                  : (Bim + (size_t)(c - 256) * 512);
    float acc = 0.f;
    for (int i = 0; i < 512; ++i) acc += bin[i] * Bsel[i];
    biasc[c] = acc * expf(gamma_log[c & 255]);
}

// ---------------- precompute combined C ----------------
__global__ __launch_bounds__(256) void prep_C(const float* __restrict__ Cre,
                                              const float* __restrict__ Cim,
                                              float* __restrict__ Cc) {
    int idx = blockIdx.x * 256 + threadIdx.x;  // 0..262143
    int o = idx >> 9;        // 0..511
    int s = idx & 511;       // 0..511
    float v = (s < 256) ? Cre[(size_t)o * 256 + s] : -Cim[(size_t)o * 256 + (s - 256)];
    Cc[idx] = v;
}

// ---------------- main GEMM: C = A @ B^T (+bias), K=512, N=512 ----------------
#define BM 128
#define BN 128
#define BK 16
__global__ __launch_bounds__(256) void gemm_abT(const float* __restrict__ A,
                                                const float* __restrict__ B,
                                                const float* __restrict__ bias,
                                                float* __restrict__ C,
                                                int Mrows) {
    __shared__ float As[BK][BM + 4];
    __shared__ float Bs[BK][BN + 4];
    const int t = threadIdx.x;
    const int row0 = blockIdx.x * BM;
    const int col0 = blockIdx.y * BN;
    const int tx = t & 15;       // 0..15 -> col group
    const int ty = t >> 4;       // 0..15 -> row group
    float acc[8][8] = {};

    for (int kt = 0; kt < KDIM; kt += BK) {
        // A tile: 128 rows x 16 k, float4 per load, transpose into As[k][m]
#pragma unroll
        for (int L = t; L < 512; L += 256) {
            int r = L >> 2;
            int kq = (L & 3) * 4;
            float4 v = make_float4(0.f, 0.f, 0.f, 0.f);
            int grow = row0 + r;
            if (grow < Mrows)
                v = *(const float4*)(A + (size_t)grow * KDIM + kt + kq);
            As[kq + 0][r] = v.x; As[kq + 1][r] = v.y;
            As[kq + 2][r] = v.z; As[kq + 3][r] = v.w;
        }
        // B tile (B is [col][K] row-major)
#pragma unroll
        for (int L = t; L < 512; L += 256) {
            int r = L >> 2;
            int kq = (L & 3) * 4;
            float4 v = *(const float4*)(B + (size_t)(col0 + r) * KDIM + kt + kq);
            Bs[kq + 0][r] = v.x; Bs[kq + 1][r] = v.y;
            Bs[kq + 2][r] = v.z; Bs[kq + 3][r] = v.w;
        }
        __syncthreads();
#pragma unroll
        for (int k = 0; k < BK; ++k) {
            float a[8], bb[8];
            *(float4*)&a[0]  = *(const float4*)&As[k][ty * 8];
            *(float4*)&a[4]  = *(const float4*)&As[k][ty * 8 + 4];
            *(float4*)&bb[0] = *(const float4*)&Bs[k][tx * 8];
            *(float4*)&bb[4] = *(const float4*)&Bs[k][tx * 8 + 4];
#pragma unroll
            for (int i = 0; i < 8; ++i)
#pragma unroll
                for (int j = 0; j < 8; ++j)
                    acc[i][j] += a[i] * bb[j];
        }
        __syncthreads();
    }

    // epilogue
#pragma unroll
    for (int i = 0; i < 8; ++i) {
        int grow = row0 + ty * 8 + i;
        if (grow >= Mrows) break;
        float* Cp = C + (size_t)grow * NCOLS + col0 + tx * 8;
        if (bias) {
#pragma unroll
            for (int j = 0; j < 8; ++j) Cp[j] = acc[i][j] + bias[col0 + tx * 8 + j];
        } else {
#pragma unroll
            for (int j = 0; j < 8; ++j) Cp[j] = acc[i][j];
        }
    }
}

// ---------------- in-place tree recurrence ----------------
// buf: [16*4095][512] where [0:256)=re, [256:512)=im; after gemm1 holds gamma*in
// which equals h at the leaf level. Levels 10..0 updated in place.
// Block owns (batch b, channel chunk of 16); dependencies are intra-block only.
__global__ __launch_bounds__(256) void tree_recur(float* __restrict__ buf,
                                                  const float* __restrict__ nu_log,
                                                  const float* __restrict__ theta_log) {
    const int b  = blockIdx.x;                    // 0..15
    const int c  = blockIdx.y * 16 + (threadIdx.x & 15);  // 0..255
    const int tn = threadIdx.x >> 4;              // 0..15
    const float lam = expf(-expf(nu_log[c]));
    const float th  = expf(theta_log[c]);
    const float lr  = lam * cosf(th);
    const float li  = lam * sinf(th);
    const size_t rowbase = (size_t)b * 4095;

    for (int d = 10; d >= 0; --d) {
        const int a = (1 << d) - 1;
        const int n = 1 << d;
        for (int i = tn; i < n; i += 16) {
            const int node = a + i;
            const size_t r  = (rowbase + node) * 512;
            const size_t rl = (rowbase + 2 * node + 1) * 512;
            const size_t rr = rl + 512;
            const float cr = buf[rl + c]       + buf[rr + c];
            const float ci = buf[rl + 256 + c] + buf[rr + 256 + c];
            const float gre = buf[r + c];
            const float gim = buf[r + 256 + c];
            buf[r + c]       = lr * cr - li * ci + gre;
            buf[r + 256 + c] = lr * ci + li * cr + gim;
        }
        __syncthreads();
    }
}

extern "C" void kernel_launch(void* const* d_in, const int* in_sizes, int n_in,
                              void* d_out, int out_size, void* d_ws, size_t ws_size,
                              hipStream_t stream) {
    const float* x         = (const float*)d_in[0];
    // d_in[1] = idx_batch (unused by reference)
    const float* W_in      = (const float*)d_in[2];
    const float* b_in      = (const float*)d_in[3];
    const float* nu_log    = (const float*)d_in[4];
    const float* theta_log = (const float*)d_in[5];
    const float* gamma_log = (const float*)d_in[6];
    const float* B_re      = (const float*)d_in[7];
    const float* B_im      = (const float*)d_in[8];
    const float* C_re      = (const float*)d_in[9];
    const float* C_im      = (const float*)d_in[10];
    float* out = (float*)d_out;

    char* ws = (char*)d_ws;
    const size_t H_BYTES = (size_t)ROWS * 512 * 4;          // 134,184,960
    float* hbuf  = (float*)ws;
    float* M     = (float*)(ws + H_BYTES);                  // 1 MB
    float* biasc = (float*)(ws + H_BYTES + (512 * 512 * 4));
    float* Cc    = (float*)(ws + H_BYTES + (512 * 512 * 4) + 2048);

    prep_M<<<dim3(32, 32), dim3(16, 16), 0, stream>>>(W_in, B_re, B_im, gamma_log, M);
    prep_bias<<<1, 512, 0, stream>>>(b_in, B_re, B_im, gamma_log, biasc);
    prep_C<<<1024, 256, 0, stream>>>(C_re, C_im, Cc);

    gemm_abT<<<dim3((ROWS + BM - 1) / BM, NCOLS / BN), 256, 0, stream>>>(x, M, biasc, hbuf, ROWS);
    tree_recur<<<dim3(16, 16), 256, 0, stream>>>(hbuf, nu_log, theta_log);
    gemm_abT<<<dim3((ROWS + BM - 1) / BM, NCOLS / BN), 256, 0, stream>>>(hbuf, Cc, nullptr, out, ROWS);
}

// Round 2
// 481.195 us; speedup vs baseline: 3.6757x; 3.6757x over previous
//
#include <hip/hip_runtime.h>

// TreeLRU: B=16, N=4095 heap, IN=OUT=512, S=256.
// Round 2: bf16 MFMA GEMMs (m97 recipe: 128x128 tile, 16x16x32 MFMA,
// global_load_lds width=16, XOR-swizzled LDS chunks), bf16 in-place tree
// recurrence as sync-free per-(batch,channel) subtree chains.
//
// Pipeline:
//   cvt_x:    x16 = bf16(x)                                  [65520 x 512]
//   prep_M:   M16[512][512] = bf16(gamma * [B_re;B_im] @ W_in)
//   prep_bias:biasc[512]    = gamma * (b_in @ B^T)   (fp32)
//   prep_C:   C16[512][512] = bf16([C_re | -C_im])
//   gemm1:    hb16 = bf16(x16 @ M16^T + biasc)   (= gamma*in = leaf h)
//   recur:    in-place bottom-up complex recurrence on hb16 (levels 10..0)
//   gemm2:    out(fp32) = hb16 @ C16^T

#define ROWS 65520
#define KDIM 512

typedef __attribute__((ext_vector_type(8))) short bf16x8;
typedef __attribute__((ext_vector_type(4))) float f32x4;

__device__ __forceinline__ unsigned short f2bf(float f) {
    unsigned int u = __float_as_uint(f);
    unsigned int r = (u + 0x7FFFu + ((u >> 16) & 1u)) >> 16;
    return (unsigned short)r;
}
__device__ __forceinline__ float b2f(unsigned short h) {
    return __uint_as_float(((unsigned int)h) << 16);
}

// ---------------- convert x to bf16 ----------------
__global__ __launch_bounds__(256) void cvt_f32_bf16(const float* __restrict__ in,
                                                    unsigned short* __restrict__ out,
                                                    int n4) {
    int i = blockIdx.x * 256 + threadIdx.x;
    if (i < n4) {
        float4 v = ((const float4*)in)[i];
        ushort4 o;
        o.x = f2bf(v.x); o.y = f2bf(v.y); o.z = f2bf(v.z); o.w = f2bf(v.w);
        ((ushort4*)out)[i] = o;
    }
}

// ---------------- precompute M (fp32 math, bf16 out) ----------------
__global__ __launch_bounds__(256) void prep_M(const float* __restrict__ W,
                                              const float* __restrict__ Bre,
                                              const float* __restrict__ Bim,
                                              const float* __restrict__ gamma_log,
                                              unsigned short* __restrict__ M16) {
    __shared__ float Bs[16][17];
    __shared__ float Ws[16][17];
    int tx = threadIdx.x, ty = threadIdx.y;
    int j  = blockIdx.x * 16 + tx;
    int cc = blockIdx.y * 16 + ty;
    const float* Bsel = (cc < 256) ? (Bre + (size_t)cc * 512)
                                   : (Bim + (size_t)(cc - 256) * 512);
    float acc = 0.f;
    for (int kt = 0; kt < 512; kt += 16) {
        Bs[ty][tx] = Bsel[kt + tx];
        Ws[ty][tx] = W[(size_t)(kt + ty) * 512 + j];
        __syncthreads();
#pragma unroll
        for (int k = 0; k < 16; ++k) acc += Bs[ty][k] * Ws[k][tx];
        __syncthreads();
    }
    float g = expf(gamma_log[cc & 255]);
    M16[(size_t)cc * 512 + j] = f2bf(acc * g);
}

__global__ void prep_bias(const float* __restrict__ bin,
                          const float* __restrict__ Bre,
                          const float* __restrict__ Bim,
                          const float* __restrict__ gamma_log,
                          float* __restrict__ biasc) {
    int c = threadIdx.x;  // 0..511
    const float* Bsel = (c < 256) ? (Bre + (size_t)c * 512)
                                  : (Bim + (size_t)(c - 256) * 512);
    float acc = 0.f;
    for (int i = 0; i < 512; ++i) acc += bin[i] * Bsel[i];
    biasc[c] = acc * expf(gamma_log[c & 255]);
}

__global__ __launch_bounds__(256) void prep_C(const float* __restrict__ Cre,
                                              const float* __restrict__ Cim,
                                              unsigned short* __restrict__ C16) {
    int idx = blockIdx.x * 256 + threadIdx.x;  // 0..262143
    int o = idx >> 9;
    int s = idx & 511;
    float v = (s < 256) ? Cre[(size_t)o * 256 + s] : -Cim[(size_t)o * 256 + (s - 256)];
    C16[idx] = f2bf(v);
}

// ---------------- bf16 MFMA GEMM: C = A @ B^T (+bias), K=N=512 ----------------
// 128x128 block tile, 4 waves, each wave 64x64 (4x4 of 16x16x32 MFMA), BK=64.
// LDS chunks (16B = 8 bf16) XOR-swizzled: stored kc holds global chunk kc^(row&7).
template <bool OUT_BF16>
__global__ __launch_bounds__(256) void gemm_mfma(const unsigned short* __restrict__ A,
                                                 const unsigned short* __restrict__ Bm,
                                                 const float* __restrict__ bias,
                                                 void* __restrict__ Cout,
                                                 int Mrows) {
    __shared__ __align__(16) unsigned short As[128 * 64];
    __shared__ __align__(16) unsigned short Bs[128 * 64];
    const int t = threadIdx.x;
    const int lane = t & 63;
    const int w = t >> 6;
    const int wr = (w >> 1) * 64;
    const int wc = (w & 1) * 64;
    const int row0 = blockIdx.x * 128;
    const int col0 = blockIdx.y * 128;

    f32x4 acc[4][4] = {};

    for (int kt = 0; kt < KDIM; kt += 64) {
#pragma unroll
        for (int q = 0; q < 4; ++q) {
            int c   = q * 256 + t;     // chunk id 0..1023
            int row = c >> 3;
            int kc  = c & 7;
            int kg  = kc ^ (row & 7);
            int ar  = row0 + row; if (ar >= Mrows) ar = Mrows - 1;
            const unsigned short* ga = A + (size_t)ar * KDIM + kt + kg * 8;
            __builtin_amdgcn_global_load_lds(
                (const __attribute__((address_space(1))) unsigned int*)ga,
                (__attribute__((address_space(3))) unsigned int*)(As + c * 8),
                16, 0, 0);
            const unsigned short* gb = Bm + (size_t)(col0 + row) * KDIM + kt + kg * 8;
            __builtin_amdgcn_global_load_lds(
                (const __attribute__((address_space(1))) unsigned int*)gb,
                (__attribute__((address_space(3))) unsigned int*)(Bs + c * 8),
                16, 0, 0);
        }
        __syncthreads();
#pragma unroll
        for (int kk = 0; kk < 64; kk += 32) {
            const int kgc = kk >> 3;  // 0 or 4
            bf16x8 af[4], bfr[4];
#pragma unroll
            for (int i = 0; i < 4; ++i) {
                int row = wr + i * 16 + (lane & 15);
                int kca = (kgc + (lane >> 4)) ^ (row & 7);
                af[i] = *(const bf16x8*)(As + row * 64 + kca * 8);
                int colr = wc + i * 16 + (lane & 15);
                int kcb = (kgc + (lane >> 4)) ^ (colr & 7);
                bfr[i] = *(const bf16x8*)(Bs + colr * 64 + kcb * 8);
            }
#pragma unroll
            for (int i = 0; i < 4; ++i)
#pragma unroll
                for (int j = 0; j < 4; ++j)
                    acc[i][j] = __builtin_amdgcn_mfma_f32_16x16x32_bf16(
                        af[i], bfr[j], acc[i][j], 0, 0, 0);
        }
        __syncthreads();
    }

    // epilogue: C/D layout col=lane&15, row=(lane>>4)*4+reg  [m89/m91 verified]
    const int cq = lane >> 4;
    const int cl = lane & 15;
#pragma unroll
    for (int i = 0; i < 4; ++i) {
#pragma unroll
        for (int j = 0; j < 4; ++j) {
#pragma unroll
            for (int r = 0; r < 4; ++r) {
                int grow = row0 + wr + i * 16 + cq * 4 + r;
                int gcol = col0 + wc + j * 16 + cl;
                if (grow < Mrows) {
                    float v = acc[i][j][r];
                    if (bias) v += bias[gcol];
                    if (OUT_BF16)
                        ((unsigned short*)Cout)[(size_t)grow * 512 + gcol] = f2bf(v);
                    else
                        ((float*)Cout)[(size_t)grow * 512 + gcol] = v;
                }
            }
        }
    }
}

// ---------------- tree recurrence (bf16 in-place, sync-free chains) ----------
// Block (b, s): subtree rooted at node 31+s (level 5), processes levels 10..5.
// Thread t owns channel t for the whole subtree -> no synchronization needed.
__global__ __launch_bounds__(256) void tree_recur_sub(unsigned short* __restrict__ buf,
                                                      const float* __restrict__ nu_log,
                                                      const float* __restrict__ theta_log) {
    const int b = blockIdx.x;
    const int s = blockIdx.y;
    const int c = threadIdx.x;
    const float lam = expf(-expf(nu_log[c]));
    const float th  = expf(theta_log[c]);
    const float lr  = lam * cosf(th);
    const float li  = lam * sinf(th);
    const size_t base = (size_t)b * 4095;
    const int rs = 31 + s;
#pragma unroll
    for (int e = 5; e >= 0; --e) {
        const int nb = ((rs + 1) << e) - 1;
        const int n  = 1 << e;
        for (int i = 0; i < n; ++i) {
            const int node = nb + i;
            const size_t r  = (base + node) * 512;
            const size_t rl = (base + 2 * node + 1) * 512;
            const size_t rr = rl + 512;
            float cr = b2f(buf[rl + c])       + b2f(buf[rr + c]);
            float ci = b2f(buf[rl + 256 + c]) + b2f(buf[rr + 256 + c]);
            float hr = lr * cr - li * ci + b2f(buf[r + c]);
            float hi = lr * ci + li * cr + b2f(buf[r + 256 + c]);
            buf[r + c]       = f2bf(hr);
            buf[r + 256 + c] = f2bf(hi);
        }
    }
}

// Levels 4..0 (31 nodes per batch), after all subtrees done.
__global__ __launch_bounds__(256) void tree_recur_top(unsigned short* __restrict__ buf,
                                                      const float* __restrict__ nu_log,
                                                      const float* __restrict__ theta_log) {
    const int b = blockIdx.x;
    const int c = threadIdx.x;
    const float lam = expf(-expf(nu_log[c]));
    const float th  = expf(theta_log[c]);
    const float lr  = lam * cosf(th);
    const float li  = lam * sinf(th);
    const size_t base = (size_t)b * 4095;
#pragma unroll
    for (int d = 4; d >= 0; --d) {
        const int a = (1 << d) - 1;
        const int n = 1 << d;
        for (int i = 0; i < n; ++i) {
            const int node = a + i;
            const size_t r  = (base + node) * 512;
            const size_t rl = (base + 2 * node + 1) * 512;
            const size_t rr = rl + 512;
            float cr = b2f(buf[rl + c])       + b2f(buf[rr + c]);
            float ci = b2f(buf[rl + 256 + c]) + b2f(buf[rr + 256 + c]);
            float hr = lr * cr - li * ci + b2f(buf[r + c]);
            float hi = lr * ci + li * cr + b2f(buf[r + 256 + c]);
            buf[r + c]       = f2bf(hr);
            buf[r + 256 + c] = f2bf(hi);
        }
    }
}

extern "C" void kernel_launch(void* const* d_in, const int* in_sizes, int n_in,
                              void* d_out, int out_size, void* d_ws, size_t ws_size,
                              hipStream_t stream) {
    const float* x         = (const float*)d_in[0];
    const float* W_in      = (const float*)d_in[2];
    const float* b_in      = (const float*)d_in[3];
    const float* nu_log    = (const float*)d_in[4];
    const float* theta_log = (const float*)d_in[5];
    const float* gamma_log = (const float*)d_in[6];
    const float* B_re      = (const float*)d_in[7];
    const float* B_im      = (const float*)d_in[8];
    const float* C_re      = (const float*)d_in[9];
    const float* C_im      = (const float*)d_in[10];
    float* out = (float*)d_out;

    char* ws = (char*)d_ws;
    const size_t HB = (size_t)ROWS * 512 * 2;   // 67,092,480 bytes
    unsigned short* x16   = (unsigned short*)ws;
    unsigned short* hb16  = (unsigned short*)(ws + HB);
    unsigned short* M16   = (unsigned short*)(ws + 2 * HB);
    unsigned short* C16   = (unsigned short*)(ws + 2 * HB + 512 * 512 * 2);
    float*          biasc = (float*)(ws + 2 * HB + 2 * 512 * 512 * 2);

    const int n4 = ROWS * 512 / 4;
    cvt_f32_bf16<<<(n4 + 255) / 256, 256, 0, stream>>>(x, x16, n4);
    prep_M<<<dim3(32, 32), dim3(16, 16), 0, stream>>>(W_in, B_re, B_im, gamma_log, M16);
    prep_bias<<<1, 512, 0, stream>>>(b_in, B_re, B_im, gamma_log, biasc);
    prep_C<<<1024, 256, 0, stream>>>(C_re, C_im, C16);

    gemm_mfma<true><<<dim3((ROWS + 127) / 128, 4), 256, 0, stream>>>(x16, M16, biasc, hb16, ROWS);
    tree_recur_sub<<<dim3(16, 32), 256, 0, stream>>>(hb16, nu_log, theta_log);
    tree_recur_top<<<16, 256, 0, stream>>>(hb16, nu_log, theta_log);
    gemm_mfma<false><<<dim3((ROWS + 127) / 128, 4), 256, 0, stream>>>(hb16, C16, nullptr, out, ROWS);
}

// Round 3
// 453.158 us; speedup vs baseline: 3.9031x; 1.0619x over previous
//
#include <hip/hip_runtime.h>

// TreeLRU: B=16, N=4095 heap, IN=OUT=512, S=256.
// Round 3: fix prep_bias (was single-block uncoalesced ~170us), GEMM grid
// swapped so consecutive blocks share the A tile, K-loop ring offset to
// decorrelate staging bursts.

#define ROWS 65520
#define KDIM 512

typedef __attribute__((ext_vector_type(8))) short bf16x8;
typedef __attribute__((ext_vector_type(4))) float f32x4;

__device__ __forceinline__ unsigned short f2bf(float f) {
    unsigned int u = __float_as_uint(f);
    unsigned int r = (u + 0x7FFFu + ((u >> 16) & 1u)) >> 16;
    return (unsigned short)r;
}
__device__ __forceinline__ float b2f(unsigned short h) {
    return __uint_as_float(((unsigned int)h) << 16);
}

// ---------------- convert x to bf16 ----------------
__global__ __launch_bounds__(256) void cvt_f32_bf16(const float* __restrict__ in,
                                                    unsigned short* __restrict__ out,
                                                    int n4) {
    int i = blockIdx.x * 256 + threadIdx.x;
    if (i < n4) {
        float4 v = ((const float4*)in)[i];
        ushort4 o;
        o.x = f2bf(v.x); o.y = f2bf(v.y); o.z = f2bf(v.z); o.w = f2bf(v.w);
        ((ushort4*)out)[i] = o;
    }
}

// ---------------- precompute M (fp32 math, bf16 out) ----------------
__global__ __launch_bounds__(256) void prep_M(const float* __restrict__ W,
                                              const float* __restrict__ Bre,
                                              const float* __restrict__ Bim,
                                              const float* __restrict__ gamma_log,
                                              unsigned short* __restrict__ M16) {
    __shared__ float Bs[16][17];
    __shared__ float Ws[16][17];
    int tx = threadIdx.x, ty = threadIdx.y;
    int j  = blockIdx.x * 16 + tx;
    int cc = blockIdx.y * 16 + ty;
    const float* Bsel = (cc < 256) ? (Bre + (size_t)cc * 512)
                                   : (Bim + (size_t)(cc - 256) * 512);
    float acc = 0.f;
    for (int kt = 0; kt < 512; kt += 16) {
        Bs[ty][tx] = Bsel[kt + tx];
        Ws[ty][tx] = W[(size_t)(kt + ty) * 512 + j];
        __syncthreads();
#pragma unroll
        for (int k = 0; k < 16; ++k) acc += Bs[ty][k] * Ws[k][tx];
        __syncthreads();
    }
    float g = expf(gamma_log[cc & 255]);
    M16[(size_t)cc * 512 + j] = f2bf(acc * g);
}

// ---------------- precompute bias: block per output channel ----------------
__global__ __launch_bounds__(64) void prep_bias(const float* __restrict__ bin,
                                                const float* __restrict__ Bre,
                                                const float* __restrict__ Bim,
                                                const float* __restrict__ gamma_log,
                                                float* __restrict__ biasc) {
    const int c = blockIdx.x;          // 0..511
    const int t = threadIdx.x;         // 0..63
    const float* Bsel = (c < 256) ? (Bre + (size_t)c * 512)
                                  : (Bim + (size_t)(c - 256) * 512);
    float acc = 0.f;
#pragma unroll
    for (int i = t; i < 512; i += 64) acc += bin[i] * Bsel[i];
#pragma unroll
    for (int off = 32; off > 0; off >>= 1) acc += __shfl_down(acc, off, 64);
    if (t == 0) biasc[c] = acc * expf(gamma_log[c & 255]);
}

__global__ __launch_bounds__(256) void prep_C(const float* __restrict__ Cre,
                                              const float* __restrict__ Cim,
                                              unsigned short* __restrict__ C16) {
    int idx = blockIdx.x * 256 + threadIdx.x;  // 0..262143
    int o = idx >> 9;
    int s = idx & 511;
    float v = (s < 256) ? Cre[(size_t)o * 256 + s] : -Cim[(size_t)o * 256 + (s - 256)];
    C16[idx] = f2bf(v);
}

// ---------------- bf16 MFMA GEMM: C = A @ B^T (+bias), K=N=512 ----------------
// 128x128 block tile, 4 waves, each wave 64x64 (4x4 of 16x16x32 MFMA), BK=64.
// grid: x = col-block (4), y = row-block (512) -> consecutive blocks share A.
// K-loop ring offset per row-block decorrelates staging bursts.
template <bool OUT_BF16>
__global__ __launch_bounds__(256) void gemm_mfma(const unsigned short* __restrict__ A,
                                                 const unsigned short* __restrict__ Bm,
                                                 const float* __restrict__ bias,
                                                 void* __restrict__ Cout,
                                                 int Mrows) {
    __shared__ __align__(16) unsigned short As[128 * 64];
    __shared__ __align__(16) unsigned short Bs[128 * 64];
    const int t = threadIdx.x;
    const int lane = t & 63;
    const int w = t >> 6;
    const int wr = (w >> 1) * 64;
    const int wc = (w & 1) * 64;
    const int row0 = blockIdx.y * 128;
    const int col0 = blockIdx.x * 128;
    const int kt0  = (blockIdx.y & 7) * 64;

    f32x4 acc[4][4] = {};

    for (int it = 0; it < 8; ++it) {
        const int kt = (kt0 + it * 64) & 511;
#pragma unroll
        for (int q = 0; q < 4; ++q) {
            int c   = q * 256 + t;     // chunk id 0..1023
            int row = c >> 3;
            int kc  = c & 7;
            int kg  = kc ^ (row & 7);
            int ar  = row0 + row; if (ar >= Mrows) ar = Mrows - 1;
            const unsigned short* ga = A + (size_t)ar * KDIM + kt + kg * 8;
            __builtin_amdgcn_global_load_lds(
                (const __attribute__((address_space(1))) unsigned int*)ga,
                (__attribute__((address_space(3))) unsigned int*)(As + c * 8),
                16, 0, 0);
            const unsigned short* gb = Bm + (size_t)(col0 + row) * KDIM + kt + kg * 8;
            __builtin_amdgcn_global_load_lds(
                (const __attribute__((address_space(1))) unsigned int*)gb,
                (__attribute__((address_space(3))) unsigned int*)(Bs + c * 8),
                16, 0, 0);
        }
        __syncthreads();
#pragma unroll
        for (int kk = 0; kk < 64; kk += 32) {
            const int kgc = kk >> 3;  // 0 or 4
            bf16x8 af[4], bfr[4];
#pragma unroll
            for (int i = 0; i < 4; ++i) {
                int row = wr + i * 16 + (lane & 15);
                int kca = (kgc + (lane >> 4)) ^ (row & 7);
                af[i] = *(const bf16x8*)(As + row * 64 + kca * 8);
                int colr = wc + i * 16 + (lane & 15);
                int kcb = (kgc + (lane >> 4)) ^ (colr & 7);
                bfr[i] = *(const bf16x8*)(Bs + colr * 64 + kcb * 8);
            }
#pragma unroll
            for (int i = 0; i < 4; ++i)
#pragma unroll
                for (int j = 0; j < 4; ++j)
                    acc[i][j] = __builtin_amdgcn_mfma_f32_16x16x32_bf16(
                        af[i], bfr[j], acc[i][j], 0, 0, 0);
        }
        __syncthreads();
    }

    // epilogue: C/D layout col=lane&15, row=(lane>>4)*4+reg  [m89/m91 verified]
    const int cq = lane >> 4;
    const int cl = lane & 15;
#pragma unroll
    for (int i = 0; i < 4; ++i) {
#pragma unroll
        for (int j = 0; j < 4; ++j) {
#pragma unroll
            for (int r = 0; r < 4; ++r) {
                int grow = row0 + wr + i * 16 + cq * 4 + r;
                int gcol = col0 + wc + j * 16 + cl;
                if (grow < Mrows) {
                    float v = acc[i][j][r];
                    if (bias) v += bias[gcol];
                    if (OUT_BF16)
                        ((unsigned short*)Cout)[(size_t)grow * 512 + gcol] = f2bf(v);
                    else
                        ((float*)Cout)[(size_t)grow * 512 + gcol] = v;
                }
            }
        }
    }
}

// ---------------- tree recurrence (bf16 in-place, sync-free chains) ----------
__global__ __launch_bounds__(256) void tree_recur_sub(unsigned short* __restrict__ buf,
                                                      const float* __restrict__ nu_log,
                                                      const float* __restrict__ theta_log) {
    const int b = blockIdx.x;
    const int s = blockIdx.y;
    const int c = threadIdx.x;
    const float lam = expf(-expf(nu_log[c]));
    const float th  = expf(theta_log[c]);
    const float lr  = lam * cosf(th);
    const float li  = lam * sinf(th);
    const size_t base = (size_t)b * 4095;
    const int rs = 31 + s;
#pragma unroll
    for (int e = 5; e >= 0; --e) {
        const int nb = ((rs + 1) << e) - 1;
        const int n  = 1 << e;
        for (int i = 0; i < n; ++i) {
            const int node = nb + i;
            const size_t r  = (base + node) * 512;
            const size_t rl = (base + 2 * node + 1) * 512;
            const size_t rr = rl + 512;
            float cr = b2f(buf[rl + c])       + b2f(buf[rr + c]);
            float ci = b2f(buf[rl + 256 + c]) + b2f(buf[rr + 256 + c]);
            float hr = lr * cr - li * ci + b2f(buf[r + c]);
            float hi = lr * ci + li * cr + b2f(buf[r + 256 + c]);
            buf[r + c]       = f2bf(hr);
            buf[r + 256 + c] = f2bf(hi);
        }
    }
}

__global__ __launch_bounds__(256) void tree_recur_top(unsigned short* __restrict__ buf,
                                                      const float* __restrict__ nu_log,
                                                      const float* __restrict__ theta_log) {
    const int b = blockIdx.x;
    const int c = threadIdx.x;
    const float lam = expf(-expf(nu_log[c]));
    const float th  = expf(theta_log[c]);
    const float lr  = lam * cosf(th);
    const float li  = lam * sinf(th);
    const size_t base = (size_t)b * 4095;
#pragma unroll
    for (int d = 4; d >= 0; --d) {
        const int a = (1 << d) - 1;
        const int n = 1 << d;
        for (int i = 0; i < n; ++i) {
            const int node = a + i;
            const size_t r  = (base + node) * 512;
            const size_t rl = (base + 2 * node + 1) * 512;
            const size_t rr = rl + 512;
            float cr = b2f(buf[rl + c])       + b2f(buf[rr + c]);
            float ci = b2f(buf[rl + 256 + c]) + b2f(buf[rr + 256 + c]);
            float hr = lr * cr - li * ci + b2f(buf[r + c]);
            float hi = lr * ci + li * cr + b2f(buf[r + 256 + c]);
            buf[r + c]       = f2bf(hr);
            buf[r + 256 + c] = f2bf(hi);
        }
    }
}

extern "C" void kernel_launch(void* const* d_in, const int* in_sizes, int n_in,
                              void* d_out, int out_size, void* d_ws, size_t ws_size,
                              hipStream_t stream) {
    const float* x         = (const float*)d_in[0];
    const float* W_in      = (const float*)d_in[2];
    const float* b_in      = (const float*)d_in[3];
    const float* nu_log    = (const float*)d_in[4];
    const float* theta_log = (const float*)d_in[5];
    const float* gamma_log = (const float*)d_in[6];
    const float* B_re      = (const float*)d_in[7];
    const float* B_im      = (const float*)d_in[8];
    const float* C_re      = (const float*)d_in[9];
    const float* C_im      = (const float*)d_in[10];
    float* out = (float*)d_out;

    char* ws = (char*)d_ws;
    const size_t HB = (size_t)ROWS * 512 * 2;   // 67,092,480 bytes
    unsigned short* x16   = (unsigned short*)ws;
    unsigned short* hb16  = (unsigned short*)(ws + HB);
    unsigned short* M16   = (unsigned short*)(ws + 2 * HB);
    unsigned short* C16   = (unsigned short*)(ws + 2 * HB + 512 * 512 * 2);
    float*          biasc = (float*)(ws + 2 * HB + 2 * 512 * 512 * 2);

    const int n4 = ROWS * 512 / 4;
    cvt_f32_bf16<<<(n4 + 255) / 256, 256, 0, stream>>>(x, x16, n4);
    prep_M<<<dim3(32, 32), dim3(16, 16), 0, stream>>>(W_in, B_re, B_im, gamma_log, M16);
    prep_bias<<<512, 64, 0, stream>>>(b_in, B_re, B_im, gamma_log, biasc);
    prep_C<<<1024, 256, 0, stream>>>(C_re, C_im, C16);

    gemm_mfma<true><<<dim3(4, (ROWS + 127) / 128), 256, 0, stream>>>(x16, M16, biasc, hb16, ROWS);
    tree_recur_sub<<<dim3(16, 32), 256, 0, stream>>>(hb16, nu_log, theta_log);
    tree_recur_top<<<16, 256, 0, stream>>>(hb16, nu_log, theta_log);
    gemm_mfma<false><<<dim3(4, (ROWS + 127) / 128), 256, 0, stream>>>(hb16, C16, nullptr, out, ROWS);
}

// Round 4
// 426.084 us; speedup vs baseline: 4.1511x; 1.0635x over previous
//
#include <hip/hip_runtime.h>

// TreeLRU: B=16, N=4095 heap, IN=OUT=512, S=256.
// Round 4: (1) XCD-aware GEMM block swizzle so the 4 col-tiles sharing an A
// row-tile land on the same XCD's L2; (2) tree recurrence rewritten as
// register-resident subtree kernels with all loads issued up-front (no
// load-after-store serialization).

#define ROWS 65520
#define KDIM 512

typedef __attribute__((ext_vector_type(8))) short bf16x8;
typedef __attribute__((ext_vector_type(4))) float f32x4;

__device__ __forceinline__ unsigned short f2bf(float f) {
    unsigned int u = __float_as_uint(f);
    unsigned int r = (u + 0x7FFFu + ((u >> 16) & 1u)) >> 16;
    return (unsigned short)r;
}
__device__ __forceinline__ float b2f(unsigned short h) {
    return __uint_as_float(((unsigned int)h) << 16);
}

// ---------------- convert x to bf16 ----------------
__global__ __launch_bounds__(256) void cvt_f32_bf16(const float* __restrict__ in,
                                                    unsigned short* __restrict__ out,
                                                    int n4) {
    int i = blockIdx.x * 256 + threadIdx.x;
    if (i < n4) {
        float4 v = ((const float4*)in)[i];
        ushort4 o;
        o.x = f2bf(v.x); o.y = f2bf(v.y); o.z = f2bf(v.z); o.w = f2bf(v.w);
        ((ushort4*)out)[i] = o;
    }
}

// ---------------- precompute M (fp32 math, bf16 out) ----------------
__global__ __launch_bounds__(256) void prep_M(const float* __restrict__ W,
                                              const float* __restrict__ Bre,
                                              const float* __restrict__ Bim,
                                              const float* __restrict__ gamma_log,
                                              unsigned short* __restrict__ M16) {
    __shared__ float Bs[16][17];
    __shared__ float Ws[16][17];
    int tx = threadIdx.x, ty = threadIdx.y;
    int j  = blockIdx.x * 16 + tx;
    int cc = blockIdx.y * 16 + ty;
    const float* Bsel = (cc < 256) ? (Bre + (size_t)cc * 512)
                                   : (Bim + (size_t)(cc - 256) * 512);
    float acc = 0.f;
    for (int kt = 0; kt < 512; kt += 16) {
        Bs[ty][tx] = Bsel[kt + tx];
        Ws[ty][tx] = W[(size_t)(kt + ty) * 512 + j];
        __syncthreads();
#pragma unroll
        for (int k = 0; k < 16; ++k) acc += Bs[ty][k] * Ws[k][tx];
        __syncthreads();
    }
    float g = expf(gamma_log[cc & 255]);
    M16[(size_t)cc * 512 + j] = f2bf(acc * g);
}

// ---------------- precompute bias: block per output channel ----------------
__global__ __launch_bounds__(64) void prep_bias(const float* __restrict__ bin,
                                                const float* __restrict__ Bre,
                                                const float* __restrict__ Bim,
                                                const float* __restrict__ gamma_log,
                                                float* __restrict__ biasc) {
    const int c = blockIdx.x;          // 0..511
    const int t = threadIdx.x;         // 0..63
    const float* Bsel = (c < 256) ? (Bre + (size_t)c * 512)
                                  : (Bim + (size_t)(c - 256) * 512);
    float acc = 0.f;
#pragma unroll
    for (int i = t; i < 512; i += 64) acc += bin[i] * Bsel[i];
#pragma unroll
    for (int off = 32; off > 0; off >>= 1) acc += __shfl_down(acc, off, 64);
    if (t == 0) biasc[c] = acc * expf(gamma_log[c & 255]);
}

__global__ __launch_bounds__(256) void prep_C(const float* __restrict__ Cre,
                                              const float* __restrict__ Cim,
                                              unsigned short* __restrict__ C16) {
    int idx = blockIdx.x * 256 + threadIdx.x;  // 0..262143
    int o = idx >> 9;
    int s = idx & 511;
    float v = (s < 256) ? Cre[(size_t)o * 256 + s] : -Cim[(size_t)o * 256 + (s - 256)];
    C16[idx] = f2bf(v);
}

// ---------------- bf16 MFMA GEMM: C = A @ B^T (+bias), K=N=512 ----------------
// 128x128 block tile, 4 waves, each wave 64x64 (4x4 of 16x16x32 MFMA), BK=64.
// 1-D grid of 2048 blocks; XCD-aware swizzle: xcd = bid&7 (round-robin
// dispatch heuristic), each XCD owns 64 consecutive row-tiles x all 4
// col-tiles, with the 4 A-sharing siblings adjacent in dispatch order.
template <bool OUT_BF16>
__global__ __launch_bounds__(256) void gemm_mfma(const unsigned short* __restrict__ A,
                                                 const unsigned short* __restrict__ Bm,
                                                 const float* __restrict__ bias,
                                                 void* __restrict__ Cout,
                                                 int Mrows) {
    __shared__ __align__(16) unsigned short As[128 * 64];
    __shared__ __align__(16) unsigned short Bs[128 * 64];
    const int t = threadIdx.x;
    const int lane = t & 63;
    const int w = t >> 6;
    const int wr = (w >> 1) * 64;
    const int wc = (w & 1) * 64;
    const int bid = blockIdx.x;
    const int xcd = bid & 7;
    const int lid = bid >> 3;               // 0..255
    const int rowblk = xcd * 64 + (lid >> 2);
    const int colblk = lid & 3;
    const int row0 = rowblk * 128;
    const int col0 = colblk * 128;
    const int kt0  = (rowblk & 7) * 64;

    f32x4 acc[4][4] = {};

    for (int it = 0; it < 8; ++it) {
        const int kt = (kt0 + it * 64) & 511;
#pragma unroll
        for (int q = 0; q < 4; ++q) {
            int c   = q * 256 + t;     // chunk id 0..1023
            int row = c >> 3;
            int kc  = c & 7;
            int kg  = kc ^ (row & 7);
            int ar  = row0 + row; if (ar >= Mrows) ar = Mrows - 1;
            const unsigned short* ga = A + (size_t)ar * KDIM + kt + kg * 8;
            __builtin_amdgcn_global_load_lds(
                (const __attribute__((address_space(1))) unsigned int*)ga,
                (__attribute__((address_space(3))) unsigned int*)(As + c * 8),
                16, 0, 0);
            const unsigned short* gb = Bm + (size_t)(col0 + row) * KDIM + kt + kg * 8;
            __builtin_amdgcn_global_load_lds(
                (const __attribute__((address_space(1))) unsigned int*)gb,
                (__attribute__((address_space(3))) unsigned int*)(Bs + c * 8),
                16, 0, 0);
        }
        __syncthreads();
#pragma unroll
        for (int kk = 0; kk < 64; kk += 32) {
            const int kgc = kk >> 3;  // 0 or 4
            bf16x8 af[4], bfr[4];
#pragma unroll
            for (int i = 0; i < 4; ++i) {
                int row = wr + i * 16 + (lane & 15);
                int kca = (kgc + (lane >> 4)) ^ (row & 7);
                af[i] = *(const bf16x8*)(As + row * 64 + kca * 8);
                int colr = wc + i * 16 + (lane & 15);
                int kcb = (kgc + (lane >> 4)) ^ (colr & 7);
                bfr[i] = *(const bf16x8*)(Bs + colr * 64 + kcb * 8);
            }
#pragma unroll
            for (int i = 0; i < 4; ++i)
#pragma unroll
                for (int j = 0; j < 4; ++j)
                    acc[i][j] = __builtin_amdgcn_mfma_f32_16x16x32_bf16(
                        af[i], bfr[j], acc[i][j], 0, 0, 0);
        }
        __syncthreads();
    }

    // epilogue: C/D layout col=lane&15, row=(lane>>4)*4+reg  [m89/m91 verified]
    const int cq = lane >> 4;
    const int cl = lane & 15;
#pragma unroll
    for (int i = 0; i < 4; ++i) {
#pragma unroll
        for (int j = 0; j < 4; ++j) {
#pragma unroll
            for (int r = 0; r < 4; ++r) {
                int grow = row0 + wr + i * 16 + cq * 4 + r;
                int gcol = col0 + wc + j * 16 + cl;
                if (grow < Mrows) {
                    float v = acc[i][j][r];
                    if (bias) v += bias[gcol];
                    if (OUT_BF16)
                        ((unsigned short*)Cout)[(size_t)grow * 512 + gcol] = f2bf(v);
                    else
                        ((float*)Cout)[(size_t)grow * 512 + gcol] = v;
                }
            }
        }
    }
}

// ---------------- tree recurrence: register-resident subtree, loads up-front.
// Block (b, s): subtree rooted at node root_base+s. E levels below the root
// are loaded as "leaf" children (already-final h values); the E levels
// root..root+E-1 are computed in fp32 registers and stored (bf16) once.
// Thread c owns channel c (re at col c, im at col 256+c). No syncs needed.
template <int E>
__global__ __launch_bounds__(256) void tree_up(unsigned short* __restrict__ buf,
                                               const float* __restrict__ nu_log,
                                               const float* __restrict__ theta_log,
                                               int root_base) {
    const int b = blockIdx.x;
    const int rs = root_base + blockIdx.y;
    const int c = threadIdx.x;
    constexpr int LEAVES = 1 << E;
    const float lam = expf(-expf(nu_log[c]));
    const float th  = expf(theta_log[c]);
    const float lr  = lam * cosf(th);
    const float li  = lam * sinf(th);
    const size_t base = (size_t)b * 4095;

    // 1) load the LEAVES finalized child states (level root+E)
    float vr[LEAVES], vi[LEAVES];
    {
        const int nbL = ((rs + 1) << E) - 1;
#pragma unroll
        for (int i = 0; i < LEAVES; ++i) {
            const size_t r = (base + nbL + i) * 512;
            vr[i] = b2f(buf[r + c]);
            vi[i] = b2f(buf[r + 256 + c]);
        }
    }
    // 2) load ALL gamma*in values for the nodes to be computed (independent)
    float gr[LEAVES - 1], gi[LEAVES - 1];
    {
        int idx = 0;
#pragma unroll
        for (int e = E - 1; e >= 0; --e) {
            const int n  = 1 << e;
            const int nb = ((rs + 1) << e) - 1;
#pragma unroll
            for (int i = 0; i < n; ++i) {
                const size_t r = (base + nb + i) * 512;
                gr[idx] = b2f(buf[r + c]);
                gi[idx] = b2f(buf[r + 256 + c]);
                ++idx;
            }
        }
    }
    // 3) compute bottom-up in registers; store each h once
    {
        int idx = 0;
#pragma unroll
        for (int e = E - 1; e >= 0; --e) {
            const int n  = 1 << e;
            const int nb = ((rs + 1) << e) - 1;
#pragma unroll
            for (int i = 0; i < n; ++i) {
                const float cr = vr[2 * i] + vr[2 * i + 1];
                const float ci = vi[2 * i] + vi[2 * i + 1];
                const float hr = lr * cr - li * ci + gr[idx];
                const float hi = lr * ci + li * cr + gi[idx];
                ++idx;
                const size_t r = (base + nb + i) * 512;
                buf[r + c]       = f2bf(hr);
                buf[r + 256 + c] = f2bf(hi);
                vr[i] = hr;
                vi[i] = hi;
            }
        }
    }
}

extern "C" void kernel_launch(void* const* d_in, const int* in_sizes, int n_in,
                              void* d_out, int out_size, void* d_ws, size_t ws_size,
                              hipStream_t stream) {
    const float* x         = (const float*)d_in[0];
    const float* W_in      = (const float*)d_in[2];
    const float* b_in      = (const float*)d_in[3];
    const float* nu_log    = (const float*)d_in[4];
    const float* theta_log = (const float*)d_in[5];
    const float* gamma_log = (const float*)d_in[6];
    const float* B_re      = (const float*)d_in[7];
    const float* B_im      = (const float*)d_in[8];
    const float* C_re      = (const float*)d_in[9];
    const float* C_im      = (const float*)d_in[10];
    float* out = (float*)d_out;

    char* ws = (char*)d_ws;
    const size_t HB = (size_t)ROWS * 512 * 2;   // 67,092,480 bytes
    unsigned short* x16   = (unsigned short*)ws;
    unsigned short* hb16  = (unsigned short*)(ws + HB);
    unsigned short* M16   = (unsigned short*)(ws + 2 * HB);
    unsigned short* C16   = (unsigned short*)(ws + 2 * HB + 512 * 512 * 2);
    float*          biasc = (float*)(ws + 2 * HB + 2 * 512 * 512 * 2);

    const int n4 = ROWS * 512 / 4;
    cvt_f32_bf16<<<(n4 + 255) / 256, 256, 0, stream>>>(x, x16, n4);
    prep_M<<<dim3(32, 32), dim3(16, 16), 0, stream>>>(W_in, B_re, B_im, gamma_log, M16);
    prep_bias<<<512, 64, 0, stream>>>(b_in, B_re, B_im, gamma_log, biasc);
    prep_C<<<1024, 256, 0, stream>>>(C_re, C_im, C16);

    gemm_mfma<true><<<2048, 256, 0, stream>>>(x16, M16, biasc, hb16, ROWS);

    // levels 10..7 (roots at level 7: nodes 127..254), then 6..3 (roots at
    // level 3: nodes 7..14), then 2..0 (root 0).
    tree_up<4><<<dim3(16, 128), 256, 0, stream>>>(hb16, nu_log, theta_log, 127);
    tree_up<4><<<dim3(16, 8),   256, 0, stream>>>(hb16, nu_log, theta_log, 7);
    tree_up<3><<<dim3(16, 1),   256, 0, stream>>>(hb16, nu_log, theta_log, 0);

    gemm_mfma<false><<<2048, 256, 0, stream>>>(hb16, C16, nullptr, out, ROWS);
}